// Round 14
// baseline (87.802 us; speedup 1.0000x reference)
//
#include <hip/hip_runtime.h>

#define NQ 12
#define NLAYERS 8
#define BATCH 1024

typedef float v2f __attribute__((ext_vector_type(2)));

// ---------------------------------------------------------------------------
// R14 = R13 pipeline (canonical layout, per-layer CNOT restore riding the LDS
// exchange, fused-RZ diagonal, permlane/DPP transport, runtime layer loop)
// with TWO STATES PER WAVE (A,B = adjacent batch elements): independent
// register-resident chains give each wave ~2x ILP so LDS latency and dep
// chains hide without co-waves. 512 blocks x 128 thr, 64KB LDS (bufA/bufB),
// 1 wave/SIMD. RZ factors & gate splats shared across A/B (state-independent).
// Index p = (wv<<11)|(lane<<5)|j ; wire w <-> bit (11-w).
// ---------------------------------------------------------------------------

constexpr int hbit(int m){ int h=0; while(m>>(h+1)) ++h; return 1<<h; }

__device__ __forceinline__ v2f vsplat(float s){ v2f v; v.x=s; v.y=s; return v; }
__device__ __forceinline__ v2f vswap(v2f v){ return __builtin_shufflevector(v, v, 1, 0); }
template<int S> __device__ __forceinline__ v2f msw(v2f v){ if constexpr (S) return vswap(v); else return v; }
__device__ __forceinline__ v2f vfma(v2f a, v2f b, v2f c){ return __builtin_elementwise_fma(a,b,c); }

template<int S>
__device__ __forceinline__ void rx_upd(v2f& ro, v2f& io, v2f r, v2f i, v2f pr, v2f pi,
                                       v2f hc2, v2f hs2, v2f ns2){
    ro = vfma(hc2, r, hs2*msw<S>(pi));
    io = vfma(hc2, i, ns2*msw<S>(pr));
}

__device__ __forceinline__ v2f bperm2(int addr, v2f v){
    v2f r;
    r.x = __int_as_float(__builtin_amdgcn_ds_bpermute(addr, __float_as_int(v.x)));
    r.y = __int_as_float(__builtin_amdgcn_ds_bpermute(addr, __float_as_int(v.y)));
    return r;
}

#if __has_builtin(__builtin_amdgcn_permlane32_swap) && __has_builtin(__builtin_amdgcn_permlane16_swap)
#define HAVE_PLSWAP 1
#else
#define HAVE_PLSWAP 0
#endif

#if HAVE_PLSWAP
// double-swap (R10/R13-verified): c1 = swap(r,i); c2 = swap(c1[1], c1[0]) ->
//   c2[0] = xorK(r), c2[1] = xorK(i)
__device__ __forceinline__ void xp32(float& pr, float& pi, float r, float i){
    auto c1 = __builtin_amdgcn_permlane32_swap(__float_as_uint(r), __float_as_uint(i), false, false);
    auto c2 = __builtin_amdgcn_permlane32_swap(c1[1], c1[0], false, false);
    pr = __uint_as_float(c2[0]);
    pi = __uint_as_float(c2[1]);
}
__device__ __forceinline__ void xp16(float& pr, float& pi, float r, float i){
    auto c1 = __builtin_amdgcn_permlane16_swap(__float_as_uint(r), __float_as_uint(i), false, false);
    auto c2 = __builtin_amdgcn_permlane16_swap(c1[1], c1[0], false, false);
    pr = __uint_as_float(c2[0]);
    pi = __uint_as_float(c2[1]);
}
#endif

// ---- DPP lane-xor (VALU pipe), LM in [1,15] (R5-proven) ----
template<int CTRL>
__device__ __forceinline__ float dpp1(float v){
    int i = __float_as_int(v);
    return __int_as_float(__builtin_amdgcn_update_dpp(i, i, CTRL, 0xF, 0xF, true));
}
template<int LM>
__device__ __forceinline__ float dppx(float v){
    static_assert(LM >= 1 && LM <= 15, "dpp xor range");
    constexpr int h = (LM >> 2) & 3;
    float r = v;
    if constexpr (h == 1 || h == 2) r = dpp1<0x141>(r);   // row_half_mirror = xor 7
    if constexpr (h == 3 || h == 2) r = dpp1<0x140>(r);   // row_mirror      = xor 15
    constexpr int st = (h==1)?7 : (h==2)?8 : (h==3)?15 : 0;
    constexpr int q = (LM ^ st) & 3;
    if constexpr (q == 1) r = dpp1<0xB1>(r);              // quad_perm xor 1
    if constexpr (q == 2) r = dpp1<0x4E>(r);              // quad_perm xor 2
    if constexpr (q == 3) r = dpp1<0x1B>(r);              // quad_perm xor 3
    return r;
}

// ---- RX, partner fully local ----
template<int JM>
__device__ __forceinline__ void rx_local(v2f (&re2)[16], v2f (&im2)[16], v2f hc2, v2f hs2, v2f ns2){
    if constexpr (JM == 1){
        #pragma unroll
        for (int t=0;t<16;++t){
            v2f r=re2[t], i=im2[t];
            rx_upd<1>(re2[t], im2[t], r, i, r, i, hc2, hs2, ns2);
        }
    } else {
        constexpr int m = JM>>1, HB = hbit(m), S = JM&1;
        #pragma unroll
        for (int t=0;t<16;++t){
            if (t & HB) continue;
            const int t2 = t ^ m;
            v2f ru=re2[t], iu=im2[t], rv=re2[t2], iv=im2[t2];
            rx_upd<S>(re2[t],  im2[t],  ru, iu, rv, iv, hc2, hs2, ns2);
            rx_upd<S>(re2[t2], im2[t2], rv, iv, ru, iu, hc2, hs2, ns2);
        }
    }
}

// ---- canonical RX on wire W (1..11); W=0 handled by exchange paths ----
template<int W>
__device__ __forceinline__ void rx_canon(v2f (&re2)[16], v2f (&im2)[16], float hc, float hs, int lane){
    const v2f hc2 = vsplat(hc), hs2 = vsplat(hs), ns2 = vsplat(-hs);
    if constexpr (W >= 1 && W <= 2){            // lane bits 5/4
#if HAVE_PLSWAP
        #pragma unroll
        for (int t=0;t<16;++t){
            v2f r=re2[t], i=im2[t];
            float prx,pix,pry,piy;
            if constexpr (W==1){ xp32(prx,pix,r.x,i.x); xp32(pry,piy,r.y,i.y); }
            else               { xp16(prx,pix,r.x,i.x); xp16(pry,piy,r.y,i.y); }
            v2f pr, pi;
            pr.x=prx; pr.y=pry; pi.x=pix; pi.y=piy;
            rx_upd<0>(re2[t], im2[t], r, i, pr, pi, hc2, hs2, ns2);
        }
#else
        const int addr = ((lane ^ (1<<(6-W))) & 63) << 2;
        #pragma unroll
        for (int t=0;t<16;++t){
            v2f r=re2[t], i=im2[t];
            v2f pi = bperm2(addr, i);
            v2f pr = bperm2(addr, r);
            rx_upd<0>(re2[t], im2[t], r, i, pr, pi, hc2, hs2, ns2);
        }
#endif
    } else if constexpr (W >= 3 && W <= 6){     // lane bits 3..0: DPP
        constexpr int LM = 1<<(6-W);
        #pragma unroll
        for (int t=0;t<16;++t){
            v2f r=re2[t], i=im2[t];
            v2f pr, pi;
            float a0=dppx<LM>(r.x), a1=dppx<LM>(r.y);
            float b0=dppx<LM>(i.x), b1=dppx<LM>(i.y);
            pr.x=a0; pr.y=a1; pi.x=b0; pi.y=b1;
            rx_upd<0>(re2[t], im2[t], r, i, pr, pi, hc2, hs2, ns2);
        }
    } else {                                    // W 7..11: local
        rx_local<(1<<(11-W))>(re2, im2, hc2, hs2, ns2);
    }
}

// ---- LDS exchange write (float4 buf[2(wv)][16(row:0-7 re,8-15 im)][64(lane)]) ----
__device__ __forceinline__ void exch_write(const v2f (&re2)[16], const v2f (&im2)[16],
                                           int lane, int wv, float4* buf){
    float4* wr = buf + (wv*16)*64 + lane;
    #pragma unroll
    for (int u=0;u<8;++u){
        float4 fr; fr.x=re2[2*u].x; fr.y=re2[2*u].y; fr.z=re2[2*u+1].x; fr.w=re2[2*u+1].y;
        float4 fi; fi.x=im2[2*u].x; fi.y=im2[2*u].y; fi.z=im2[2*u+1].x; fi.w=im2[2*u+1].y;
        wr[u*64]     = fr;
        wr[(8+u)*64] = fi;
    }
}

// ---- CNOT-ladder permute gather + RX(w0), fused in one exchange read (R11-verified) ----
__device__ __forceinline__ void perm_rx0(v2f (&re2)[16], v2f (&im2)[16],
                                         float hc, float hs, int lane, int wv,
                                         const float4* buf){
    const v2f hc2 = vsplat(hc), hs2 = vsplat(hs), ns2 = vsplat(-hs);
    const int sl = ((lane ^ (lane>>1)) & 63) ^ (wv<<5);
    const int rb = (lane & 1) << 2;
    const float4* rdS = buf + (wv*16)*64 + sl;
    const float4* rdP = buf + ((wv^1)*16)*64 + (sl^32);
    #pragma unroll
    for (int u=0;u<8;++u){
        const int row = (u ^ (u>>1)) ^ rb;
        float4 Fr = rdS[row*64], Fi = rdS[(row+8)*64];
        float4 Gr = rdP[row*64], Gi = rdP[(row+8)*64];
        v2f ar,ai,br,bi, pr,pi,qr,qi;
        if ((u & 1) == 0){   // dest (k0..k3) <- src (x,y,w,z)
            ar.x=Fr.x; ar.y=Fr.y;  br.x=Fr.w; br.y=Fr.z;
            ai.x=Fi.x; ai.y=Fi.y;  bi.x=Fi.w; bi.y=Fi.z;
            pr.x=Gr.x; pr.y=Gr.y;  qr.x=Gr.w; qr.y=Gr.z;
            pi.x=Gi.x; pi.y=Gi.y;  qi.x=Gi.w; qi.y=Gi.z;
        } else {             // dest (k0..k3) <- src (z,w,y,x)
            ar.x=Fr.z; ar.y=Fr.w;  br.x=Fr.y; br.y=Fr.x;
            ai.x=Fi.z; ai.y=Fi.w;  bi.x=Fi.y; bi.y=Fi.x;
            pr.x=Gr.z; pr.y=Gr.w;  qr.x=Gr.y; qr.y=Gr.x;
            pi.x=Gi.z; pi.y=Gi.w;  qi.x=Gi.y; qi.y=Gi.x;
        }
        rx_upd<0>(re2[2*u],   im2[2*u],   ar, ai, pr, pi, hc2, hs2, ns2);
        rx_upd<0>(re2[2*u+1], im2[2*u+1], br, bi, qr, qi, hc2, hs2, ns2);
    }
}

// ---- init-time RX(w0) read half (write+bar done by caller) ----
__device__ __forceinline__ void init_rx0_read(v2f (&re2)[16], v2f (&im2)[16],
                                              float hc, float hs, int lane, int wv,
                                              const float4* buf){
    const v2f hc2 = vsplat(hc), hs2 = vsplat(hs), ns2 = vsplat(-hs);
    const float4* rd = buf + ((wv^1)*16)*64 + lane;
    #pragma unroll
    for (int u=0;u<8;++u){
        float4 Fr = rd[u*64], Fi = rd[(u+8)*64];
        v2f prl,pil,prh,pih;
        prl.x=Fr.x; prl.y=Fr.y; prh.x=Fr.z; prh.y=Fr.w;
        pil.x=Fi.x; pil.y=Fi.y; pih.x=Fi.z; pih.y=Fi.w;
        rx_upd<0>(re2[2*u],   im2[2*u],   re2[2*u],   im2[2*u],   prl, pil, hc2, hs2, ns2);
        rx_upd<0>(re2[2*u+1], im2[2*u+1], re2[2*u+1], im2[2*u+1], prh, pih, hc2, hs2, ns2);
    }
}

// ---- per-layer RX gates w1..w11 for BOTH states (A then B per wire) ----
template<int W>
__device__ __forceinline__ void gatesAB(v2f (&Ar)[16], v2f (&Ai)[16],
                                        v2f (&Br)[16], v2f (&Bi)[16],
                                        const float2* __restrict__ tb, int lane){
    const float2 t = tb[W];
    rx_canon<W>(Ar, Ai, t.x, t.y, lane);
    rx_canon<W>(Br, Bi, t.x, t.y, lane);
    if constexpr (W+1 < NQ) gatesAB<W+1>(Ar, Ai, Br, Bi, tb, lane);
}

// ---- init RX w1..w11 for both states ----
template<int W>
__device__ __forceinline__ void init_wAB(v2f (&Ar)[16], v2f (&Ai)[16],
                                         v2f (&Br)[16], v2f (&Bi)[16],
                                         const float* __restrict__ xb0,
                                         const float* __restrict__ xb1, int lane){
    float hs0, hc0, hs1, hc1;
    __sincosf(xb0[W]*1.5707963267948966f, &hs0, &hc0);
    __sincosf(xb1[W]*1.5707963267948966f, &hs1, &hc1);
    rx_canon<W>(Ar, Ai, hc0, hs0, lane);
    rx_canon<W>(Br, Bi, hc1, hs1, lane);
    if constexpr (W+1 < NQ) init_wAB<W+1>(Ar, Ai, Br, Bi, xb0, xb1, lane);
}

// ---------------------------------------------------------------------------
// Workspace layout (floats): [0,192) tRX float2[8][12]; [192,256) tTH f[8][8];
//                            [256,768) tJ float4[8][16]
// ---------------------------------------------------------------------------
__global__ void prep_kernel(const float* __restrict__ P, float* __restrict__ ws){
    const int i = threadIdx.x;   // 128 threads
    float2* tRX = (float2*)ws;
    float*  tTH = ws + 192;
    float4* tJ  = (float4*)(ws + 256);
    if (i < 96){
        const int l = i/12, w = i%12;
        float2 v; __sincosf(P[l*24 + 2*w]*0.5f, &v.y, &v.x);
        tRX[i] = v;
    }
    if (i < 64){
        const int l = i>>3, w = i&7;
        tTH[i] = (w < 7) ? P[l*24 + 2*w + 1]*0.5f : 0.f;
    }
    {
        const int l = i>>4, t = i&15;
        float br[2], bi[2];
        #pragma unroll
        for (int k=0;k<2;++k){
            const int j = 2*t + k;
            float beta = 0.f;
            #pragma unroll
            for (int w=7; w<12; ++w){
                const float th = P[l*24 + 2*w + 1]*0.5f;
                beta += ((j >> (11-w)) & 1) ? th : -th;
            }
            __sincosf(beta, &bi[k], &br[k]);
        }
        float4 v; v.x=br[0]; v.y=br[1]; v.z=bi[0]; v.w=bi[1];
        tJ[i] = v;
    }
}

__global__ __launch_bounds__(128, 1) void qnn_kernel(const float* __restrict__ x,
                                                     const float* __restrict__ ws,
                                                     const float* __restrict__ Wm,
                                                     float* __restrict__ out)
{
    __shared__ float4 lds4[4096];   // 64 KB: bufA | bufB
    float4* bufA = lds4;
    float4* bufB = lds4 + 2048;
    const int lane = threadIdx.x & 63;
    const int wv   = threadIdx.x >> 6;
    const int b0   = blockIdx.x*2;
    const int b1   = b0 + 1;

    const float2* tRX = (const float2*)ws;
    const float*  tTH = ws + 192;
    const float4* tJ  = (const float4*)(ws + 256);

    v2f Ar[16], Ai[16], Br[16], Bi[16];
    #pragma unroll
    for (int t=0;t<16;++t){
        Ar[t]=vsplat(0.f); Ai[t]=vsplat(0.f);
        Br[t]=vsplat(0.f); Bi[t]=vsplat(0.f);
    }
    if (threadIdx.x == 0){ Ar[0].x = 1.0f; Br[0].x = 1.0f; }

    const float* xb0 = x + b0*NQ;
    const float* xb1 = x + b1*NQ;
    init_wAB<1>(Ar, Ai, Br, Bi, xb0, xb1, lane);
    {
        float hsA, hcA, hsB, hcB;
        __sincosf(xb0[0]*1.5707963267948966f, &hsA, &hcA);
        __sincosf(xb1[0]*1.5707963267948966f, &hsB, &hcB);
        exch_write(Ar, Ai, lane, wv, bufA);
        exch_write(Br, Bi, lane, wv, bufB);
        __syncthreads();
        init_rx0_read(Ar, Ai, hcA, hsA, lane, wv, bufA);
        init_rx0_read(Br, Bi, hcB, hsB, lane, wv, bufB);
        __syncthreads();
    }

    #pragma unroll 1
    for (int l = 0; l < NLAYERS; ++l){
        const float2* tb = tRX + l*12;
        const float2 t0 = tb[0];
        exch_write(Ar, Ai, lane, wv, bufA);
        exch_write(Br, Bi, lane, wv, bufB);
        __syncthreads();
        perm_rx0(Ar, Ai, t0.x, t0.y, lane, wv, bufA);   // CNOT restore + RX(w0), A
        perm_rx0(Br, Bi, t0.x, t0.y, lane, wv, bufB);   // same for B (independent)
        gatesAB<1>(Ar, Ai, Br, Bi, tb, lane);           // RX w1..w11, A/B interleaved

        // ---- fused RZ: factors shared by A and B ----
        const float* th = tTH + l*8;
        float alpha = wv ? th[0] : -th[0];
        #pragma unroll
        for (int w=1; w<=6; ++w)
            alpha += ((lane >> (6-w)) & 1) ? th[w] : -th[w];
        float sa, ca;
        __sincosf(alpha, &sa, &ca);
        const v2f vca = vsplat(ca), vsa = vsplat(sa), vna = vsplat(-sa);
        const float4* tj = tJ + l*16;
        #pragma unroll
        for (int t=0;t<16;++t){
            const float4 J = tj[t];
            v2f jr; jr.x=J.x; jr.y=J.y;
            v2f ji; ji.x=J.z; ji.y=J.w;
            const v2f cr  = vfma(vca, jr, vna*ji);
            const v2f ci  = vfma(vca, ji, vsa*jr);
            const v2f nci = -ci;
            v2f r, m;
            r = Ar[t]; m = Ai[t];
            Ar[t] = vfma(r, cr, m*nci);
            Ai[t] = vfma(m, cr, r*ci);
            r = Br[t]; m = Bi[t];
            Br[t] = vfma(r, cr, m*nci);
            Bi[t] = vfma(m, cr, r*ci);
        }
        __syncthreads();
    }

    // ---- PauliZ expvals for both states ----
    v2f SA = vsplat(0.f), SA7 = vsplat(0.f), SA8 = vsplat(0.f), SA9 = vsplat(0.f), SA10 = vsplat(0.f);
    v2f SB = vsplat(0.f), SB7 = vsplat(0.f), SB8 = vsplat(0.f), SB9 = vsplat(0.f), SB10 = vsplat(0.f);
    #pragma unroll
    for (int t=0;t<16;++t){
        v2f pa = __builtin_elementwise_fma(Ar[t], Ar[t], Ai[t]*Ai[t]);
        v2f pb = __builtin_elementwise_fma(Br[t], Br[t], Bi[t]*Bi[t]);
        SA += pa;  SB += pb;
        SA7  += (t&8)? -pa : pa;   SB7  += (t&8)? -pb : pb;
        SA8  += (t&4)? -pa : pa;   SB8  += (t&4)? -pb : pb;
        SA9  += (t&2)? -pa : pa;   SB9  += (t&2)? -pb : pb;
        SA10 += (t&1)? -pa : pa;   SB10 += (t&1)? -pb : pb;
    }
    const float sA0 = SA.x + SA.y;
    const float sB0 = SB.x + SB.y;

    float zA[12], zB[12];
    zA[0] = wv ? -sA0 : sA0;  zB[0] = wv ? -sB0 : sB0;
    #pragma unroll
    for (int w=1; w<=6; ++w){
        const bool f = (lane >> (6-w)) & 1;
        zA[w] = f ? -sA0 : sA0;
        zB[w] = f ? -sB0 : sB0;
    }
    zA[7]  = SA7.x + SA7.y;    zB[7]  = SB7.x + SB7.y;
    zA[8]  = SA8.x + SA8.y;    zB[8]  = SB8.x + SB8.y;
    zA[9]  = SA9.x + SA9.y;    zB[9]  = SB9.x + SB9.y;
    zA[10] = SA10.x + SA10.y;  zB[10] = SB10.x + SB10.y;
    zA[11] = SA.x - SA.y;      zB[11] = SB.x - SB.y;

    #pragma unroll
    for (int m=1; m<64; m<<=1){
        #pragma unroll
        for (int w=0; w<12; ++w){
            zA[w] += __shfl_xor(zA[w], m, 64);
            zB[w] += __shfl_xor(zB[w], m, 64);
        }
    }

    float* sh = (float*)lds4;
    if (lane == 0){
        #pragma unroll
        for (int w=0; w<12; ++w){
            sh[wv*12 + w]      = zA[w];
            sh[24 + wv*12 + w] = zB[w];
        }
    }
    __syncthreads();
    if (wv == 0){
        float tA = 0.f, tB = 0.f;
        if (lane < 12){
            #pragma unroll
            for (int w=0; w<12; ++w){
                const float wm = Wm[w*12 + lane];
                tA = fmaf(sh[w]      + sh[12+w], wm, tA);
                tB = fmaf(sh[24+w]   + sh[36+w], wm, tB);
            }
            tA = fmaxf(tA, 0.f);
            tB = fmaxf(tB, 0.f);
        }
        #pragma unroll
        for (int m=1; m<16; m<<=1){
            tA += __shfl_xor(tA, m, 64);
            tB += __shfl_xor(tB, m, 64);
        }
        if (lane == 0){ out[b0] = tA; out[b1] = tB; }
    }
}

extern "C" void kernel_launch(void* const* d_in, const int* in_sizes, int n_in,
                              void* d_out, int out_size, void* d_ws, size_t ws_size,
                              hipStream_t stream) {
    const float* x  = (const float*)d_in[0];
    const float* P  = (const float*)d_in[1];
    const float* Wm = (const float*)d_in[2];
    float* out = (float*)d_out;
    float* ws  = (float*)d_ws;    // 768 floats = 3 KB
    prep_kernel<<<1, 128, 0, stream>>>(P, ws);
    qnn_kernel<<<BATCH/2, 128, 0, stream>>>(x, ws, Wm, out);
}